// Round 3
// baseline (418.624 us; speedup 1.0000x reference)
//
#include <hip/hip_runtime.h>

#define NN 50000
#define SNEI 16

typedef unsigned short ushort_t;
typedef unsigned int uint_t;
typedef unsigned long long u64;
typedef __attribute__((ext_vector_type(8))) short bhalf8;
typedef __attribute__((ext_vector_type(4))) float facc4;

__device__ __forceinline__ float b2f(uint_t u) {
    union { uint_t u; float f; } x; x.u = u << 16; return x.f;
}
__device__ __forceinline__ ushort_t f2b(float f) {
    union { float f; uint_t u; } x; x.f = f;
    return (ushort_t)((x.u + 0x7FFFu + ((x.u >> 16) & 1u)) >> 16);
}
__device__ __forceinline__ u64 pack4(float a, float b, float c, float d) {
    return (u64)f2b(a) | ((u64)f2b(b) << 16) | ((u64)f2b(c) << 32) | ((u64)f2b(d) << 48);
}

// ---------------------------------------------------------------------------
// One-time weight permute (fp32 -> bf16) into B-fragment-major order.
// Chunk layout: chunk = (ks*8 + nf)*64 + lane, 8 bf16 per chunk.
// Element j of lane l holds W[k][c] with
//   k = ks*32 + 16*(j>>2) + (l>>4)*4 + (j&3),  c = nf*16 + (l&15).
// Same bijection is used by A-staging, so the MFMA contraction is exact.
// ---------------------------------------------------------------------------
__global__ void permW(const float* __restrict__ prepW,
                      const float* __restrict__ Wx1, const float* __restrict__ Wn1,
                      const float* __restrict__ Wx2, const float* __restrict__ Wn2,
                      ushort_t* __restrict__ dst)
{
    int cid = blockIdx.x * 256 + threadIdx.x;           // 28672 total
    const float* src; int K, hk, q, dbase;
    if (cid < 4096)       { src = prepW; K = 256; hk = 0; q = cid; dbase = 0; }
    else if (cid < 8192)  { int m = cid - 4096;  int mp = m >> 11; q = m & 2047; src = Wx1 + mp*16384; K = 128; hk = 1; dbase = 4096  + mp*2048; }
    else if (cid < 12288) { int m = cid - 8192;  int mp = m >> 11; q = m & 2047; src = Wn1 + mp*16384; K = 128; hk = 1; dbase = 8192  + mp*2048; }
    else if (cid < 20480) { int m = cid - 12288; int mp = m >> 12; q = m & 4095; src = Wx2 + mp*32768; K = 256; hk = 1; dbase = 12288 + mp*4096; }
    else                  { int m = cid - 20480; int mp = m >> 12; q = m & 4095; src = Wn2 + mp*32768; K = 256; hk = 1; dbase = 20480 + mp*4096; }
    int lane = q & 63, nf = (q >> 6) & 7, ks = q >> 9;
    int cl = lane & 15, g = lane >> 4;
    int c = nf * 16 + cl;
    ushort_t tmp[8];
#pragma unroll
    for (int j = 0; j < 8; ++j) {
        int k = ks*32 + ((j >> 2) << 4) + g*4 + (j & 3);
        int sidx = hk ? (((c >> 6)*K + k)*64 + (c & 63)) : (k*128 + c);
        tmp[j] = f2b(src[sidx]);
    }
    u64 lo = (u64)tmp[0] | ((u64)tmp[1] << 16) | ((u64)tmp[2] << 32) | ((u64)tmp[3] << 48);
    u64 hi = (u64)tmp[4] | ((u64)tmp[5] << 16) | ((u64)tmp[6] << 32) | ((u64)tmp[7] << 48);
    u64* o = (u64*)(dst + (size_t)(dbase + q) * 8);
    o[0] = lo; o[1] = hi;
}

// ---------------------------------------------------------------------------
// Prep GEMM: h0 = bf16(feats @ prep_W), [50000,256]x[256,128].
// Tile 64 rows, 4 waves (2 along M x 2 along N), BK=64, fragment-major LDS.
// ---------------------------------------------------------------------------
__global__ __launch_bounds__(256, 2)
void prep_gemm(const float* __restrict__ X, const ushort_t* __restrict__ Wp,
               ushort_t* __restrict__ outb)
{
    __shared__ bhalf8 lds[1536];
    u64* l64 = (u64*)lds;
    const int tid = threadIdx.x;
    const int lane = tid & 63;
    const int wid = tid >> 6;
    const int wave_m = wid >> 1, wave_n = wid & 1;
    const int m0 = blockIdx.x * 64;

    facc4 acc[2][4];
    const facc4 z = {0.f, 0.f, 0.f, 0.f};
#pragma unroll
    for (int i = 0; i < 2; ++i)
#pragma unroll
        for (int j = 0; j < 4; ++j) acc[i][j] = z;

    for (int kt = 0; kt < 4; ++kt) {
#pragma unroll
        for (int it = 0; it < 2; ++it) {
            int idx = tid + it * 256;
            int row = idx >> 3, a = idx & 7;
            int grow = m0 + row; if (grow > NN - 1) grow = NN - 1;
            const float4* gp = (const float4*)(X + (size_t)grow * 256 + kt*64 + a*8);
            float4 f0 = gp[0], f1 = gp[1];
            int a2 = a & 3, half = a2 >> 1, g1 = (a2 & 1) << 1;
            int cb = ((a >> 2)*4 + (row >> 4))*64 + (row & 15);
            l64[(cb + g1*16)*2 + half]       = pack4(f0.x, f0.y, f0.z, f0.w);
            l64[(cb + (g1 + 1)*16)*2 + half] = pack4(f1.x, f1.y, f1.z, f1.w);
        }
        {
            const bhalf8* wg = (const bhalf8*)Wp + (size_t)kt * 1024;
#pragma unroll
            for (int it = 0; it < 4; ++it) {
                int idx = tid + it * 256;
                lds[512 + idx] = wg[idx];
            }
        }
        __syncthreads();
        const int nfo = wave_n * 4;
#pragma unroll
        for (int ksl = 0; ksl < 2; ++ksl) {
            bhalf8 a0 = lds[(ksl*4 + wave_m*2 + 0)*64 + lane];
            bhalf8 a1 = lds[(ksl*4 + wave_m*2 + 1)*64 + lane];
#pragma unroll
            for (int nf = 0; nf < 4; ++nf) {
                bhalf8 b = lds[512 + (ksl*8 + nfo + nf)*64 + lane];
                acc[0][nf] = __builtin_amdgcn_mfma_f32_16x16x32_bf16(a0, b, acc[0][nf], 0, 0, 0);
                acc[1][nf] = __builtin_amdgcn_mfma_f32_16x16x32_bf16(a1, b, acc[1][nf], 0, 0, 0);
            }
        }
        __syncthreads();
    }
    const int cl = lane & 15, rg = lane >> 4;
#pragma unroll
    for (int mf2 = 0; mf2 < 2; ++mf2) {
        int rowb = m0 + (wave_m*2 + mf2)*16 + rg*4;
#pragma unroll
        for (int nf = 0; nf < 4; ++nf) {
            int col = (wave_n*4 + nf)*16 + cl;
            facc4 v = acc[mf2][nf];
#pragma unroll
            for (int rr = 0; rr < 4; ++rr) {
                int row = rowb + rr;
                if (row < NN) outb[(size_t)row * 128 + col] = f2b(v[rr]);
            }
        }
    }
}

// ---------------------------------------------------------------------------
// Fused layer GEMM: per 64-row tile, gather-mean of 16 neighbors is computed
// during LDS staging (fragment-major), wave_n=0 -> X@Wx, wave_n=1 -> AGG@Wn,
// relu, head-interleaved fp32 out [., pitch 512] at ocol0.
// WRH1: also write bf16 copy of the (relu'd) output to h1o [NN,256].
// h: bf16 input [NN, ph] (ph = K). neigh tile cached in LDS.
// ---------------------------------------------------------------------------
template<bool WRH1>
__global__ __launch_bounds__(256, 2)
void fused_gemm(const ushort_t* __restrict__ h, int ph,
                const int* __restrict__ nb,
                const ushort_t* __restrict__ Wxp, const ushort_t* __restrict__ Wnp,
                int K, float* __restrict__ out, int ocol0,
                ushort_t* __restrict__ h1o)
{
    __shared__ bhalf8 lds[3072];
    __shared__ int nls[1024];
    u64* l64 = (u64*)lds;
    const int tid = threadIdx.x;
    const int lane = tid & 63;
    const int wid = tid >> 6;
    const int wave_m = wid >> 1, wave_n = wid & 1;
    const int m0 = blockIdx.x * 64;

    {   // stage neighbor tile: 64 rows x 16 ints
        int r = tid >> 2;
        int grow = m0 + r; if (grow > NN - 1) grow = NN - 1;
        ((int4*)nls)[tid] = ((const int4*)(nb + (size_t)grow * SNEI))[tid & 3];
    }

    facc4 acc[2][8];
    const facc4 z = {0.f, 0.f, 0.f, 0.f};
#pragma unroll
    for (int i = 0; i < 2; ++i)
#pragma unroll
        for (int j = 0; j < 8; ++j) acc[i][j] = z;

    __syncthreads();                               // nls ready
    const int K64 = K >> 6;
    for (int kt = 0; kt < K64; ++kt) {
#pragma unroll
        for (int it = 0; it < 2; ++it) {
            int idx = tid + it * 256;              // (row, 8-elem chunk a)
            int row = idx >> 3, a = idx & 7;
            int grow = m0 + row; if (grow > NN - 1) grow = NN - 1;
            int coff = kt*64 + a*8;
            int a2 = a & 3, half = a2 >> 1, g1 = (a2 & 1) << 1;
            int cb = ((a >> 2)*4 + (row >> 4))*64 + (row & 15);
            // X operand (bf16 passthrough)
            const u64* gp = (const u64*)(h + (size_t)grow * ph + coff);
            l64[(cb + g1*16)*2 + half]       = gp[0];
            l64[(cb + (g1 + 1)*16)*2 + half] = gp[1];
            // AGG operand: 16-neighbor mean, computed in fp32
            float s0=0.f,s1=0.f,s2=0.f,s3=0.f,s4=0.f,s5=0.f,s6=0.f,s7=0.f;
            const int* nrow = nls + row * SNEI;
#pragma unroll
            for (int t = 0; t < SNEI; ++t) {
                int n2 = nrow[t];
                uint4 v = *(const uint4*)(h + (size_t)n2 * ph + coff);
                s0 += b2f(v.x & 0xFFFFu); s1 += b2f(v.x >> 16);
                s2 += b2f(v.y & 0xFFFFu); s3 += b2f(v.y >> 16);
                s4 += b2f(v.z & 0xFFFFu); s5 += b2f(v.z >> 16);
                s6 += b2f(v.w & 0xFFFFu); s7 += b2f(v.w >> 16);
            }
            const float C = 0.0625f;
            l64[1024 + (cb + g1*16)*2 + half]       = pack4(s0*C, s1*C, s2*C, s3*C);
            l64[1024 + (cb + (g1 + 1)*16)*2 + half] = pack4(s4*C, s5*C, s6*C, s7*C);
        }
        {   // W stage (linear copy of pre-permuted chunks)
            const bhalf8* wgx = (const bhalf8*)Wxp + (size_t)kt * 1024;
            const bhalf8* wgn = (const bhalf8*)Wnp + (size_t)kt * 1024;
#pragma unroll
            for (int it = 0; it < 4; ++it) {
                int idx = tid + it * 256;
                lds[1024 + idx] = wgx[idx];
                lds[2048 + idx] = wgn[idx];
            }
        }
        __syncthreads();
        const int aB = wave_n ? 512 : 0;
        const int wB = wave_n ? 2048 : 1024;
#pragma unroll
        for (int ksl = 0; ksl < 2; ++ksl) {
            bhalf8 a0 = lds[aB + (ksl*4 + wave_m*2 + 0)*64 + lane];
            bhalf8 a1 = lds[aB + (ksl*4 + wave_m*2 + 1)*64 + lane];
#pragma unroll
            for (int nf = 0; nf < 8; ++nf) {
                bhalf8 b = lds[wB + (ksl*8 + nf)*64 + lane];
                acc[0][nf] = __builtin_amdgcn_mfma_f32_16x16x32_bf16(a0, b, acc[0][nf], 0, 0, 0);
                acc[1][nf] = __builtin_amdgcn_mfma_f32_16x16x32_bf16(a1, b, acc[1][nf], 0, 0, 0);
            }
        }
        __syncthreads();
    }
    // epilogue: D mapping col=lane&15, row=(lane>>4)*4+reg; relu; interleave
    const int cl = lane & 15, rg = lane >> 4;
#pragma unroll
    for (int mf2 = 0; mf2 < 2; ++mf2) {
        int rowb = m0 + (wave_m*2 + mf2)*16 + rg*4;
#pragma unroll
        for (int nf = 0; nf < 8; ++nf) {
            int cpr = nf*16 + cl;
            int icol = (cpr >> 6)*128 + wave_n*64 + (cpr & 63);
            facc4 v = acc[mf2][nf];
#pragma unroll
            for (int rr = 0; rr < 4; ++rr) {
                int row = rowb + rr;
                if (row < NN) {
                    float f = fmaxf(v[rr], 0.0f);
                    out[(size_t)row * 512 + ocol0 + icol] = f;
                    if constexpr (WRH1)
                        h1o[(size_t)row * 256 + icol] = f2b(f);
                }
            }
        }
    }
}

// ---------------------------------------------------------------------------
extern "C" void kernel_launch(void* const* d_in, const int* in_sizes, int n_in,
                              void* d_out, int out_size, void* d_ws, size_t ws_size,
                              hipStream_t stream)
{
    const float* feats  = (const float*)d_in[0];
    const float* prepWp = (const float*)d_in[1];
    const float* Wx1    = (const float*)d_in[2];
    const float* Wn1    = (const float*)d_in[3];
    const float* Wx2    = (const float*)d_in[4];
    const float* Wn2    = (const float*)d_in[5];
    const int*   neigh  = (const int*)d_in[6];
    float* out = (float*)d_out;
    ushort_t* ws = (ushort_t*)d_ws;

    ushort_t* perm = ws;                          // 229376 bf16 (458.75 KB)
    ushort_t* h0   = ws + 229376;                 // 50000*128 bf16 (12.8 MB)
    ushort_t* h1   = h0 + (size_t)NN * 128;       // 50000*256 bf16 (25.6 MB)

    permW<<<112, 256, 0, stream>>>(prepWp, Wx1, Wn1, Wx2, Wn2, perm);

    const int GB = (NN + 63) / 64;                // 782
    prep_gemm<<<GB, 256, 0, stream>>>(feats, perm, h0);

    for (int mp = 0; mp < 2; ++mp) {
        float* omp = out + (size_t)mp * NN * 512;
        const int* nmp = neigh + (size_t)mp * NN * SNEI;

        fused_gemm<true><<<GB, 256, 0, stream>>>(h0, 128, nmp,
            perm + (size_t)(4096  + mp*2048) * 8,
            perm + (size_t)(8192  + mp*2048) * 8,
            128, omp, 0, h1);

        fused_gemm<false><<<GB, 256, 0, stream>>>(h1, 256, nmp,
            perm + (size_t)(12288 + mp*4096) * 8,
            perm + (size_t)(20480 + mp*4096) * 8,
            256, omp, 256, nullptr);
    }
}

// Round 4
// 277.409 us; speedup vs baseline: 1.5091x; 1.5091x over previous
//
#include <hip/hip_runtime.h>

#define NN 50000
#define SNEI 16

typedef unsigned short ushort_t;
typedef unsigned int uint_t;
typedef unsigned long long u64;
typedef __attribute__((ext_vector_type(8))) short bhalf8;
typedef __attribute__((ext_vector_type(4))) float facc4;

__device__ __forceinline__ float b2f(uint_t u) {
    union { uint_t u; float f; } x; x.u = u << 16; return x.f;
}
__device__ __forceinline__ ushort_t f2b(float f) {
    union { float f; uint_t u; } x; x.f = f;
    return (ushort_t)((x.u + 0x7FFFu + ((x.u >> 16) & 1u)) >> 16);
}
__device__ __forceinline__ u64 pack4(float a, float b, float c, float d) {
    return (u64)f2b(a) | ((u64)f2b(b) << 16) | ((u64)f2b(c) << 32) | ((u64)f2b(d) << 48);
}

// ---------------------------------------------------------------------------
// One-time weight permute (fp32 -> bf16) into B-fragment-major order.
// Chunk layout: chunk = (ks*8 + nf)*64 + lane, 8 bf16 per chunk.
// Element j of lane l holds W[k][c] with
//   k = ks*32 + 16*(j>>2) + (l>>4)*4 + (j&3),  c = nf*16 + (l&15).
// Same bijection is used by A-staging, so the MFMA contraction is exact.
// ---------------------------------------------------------------------------
__global__ void permW(const float* __restrict__ prepW,
                      const float* __restrict__ Wx1, const float* __restrict__ Wn1,
                      const float* __restrict__ Wx2, const float* __restrict__ Wn2,
                      ushort_t* __restrict__ dst)
{
    int cid = blockIdx.x * 256 + threadIdx.x;           // 28672 total
    const float* src; int K, hk, q, dbase;
    if (cid < 4096)       { src = prepW; K = 256; hk = 0; q = cid; dbase = 0; }
    else if (cid < 8192)  { int m = cid - 4096;  int mp = m >> 11; q = m & 2047; src = Wx1 + mp*16384; K = 128; hk = 1; dbase = 4096  + mp*2048; }
    else if (cid < 12288) { int m = cid - 8192;  int mp = m >> 11; q = m & 2047; src = Wn1 + mp*16384; K = 128; hk = 1; dbase = 8192  + mp*2048; }
    else if (cid < 20480) { int m = cid - 12288; int mp = m >> 12; q = m & 4095; src = Wx2 + mp*32768; K = 256; hk = 1; dbase = 12288 + mp*4096; }
    else                  { int m = cid - 20480; int mp = m >> 12; q = m & 4095; src = Wn2 + mp*32768; K = 256; hk = 1; dbase = 20480 + mp*4096; }
    int lane = q & 63, nf = (q >> 6) & 7, ks = q >> 9;
    int cl = lane & 15, g = lane >> 4;
    int c = nf * 16 + cl;
    ushort_t tmp[8];
#pragma unroll
    for (int j = 0; j < 8; ++j) {
        int k = ks*32 + ((j >> 2) << 4) + g*4 + (j & 3);
        int sidx = hk ? (((c >> 6)*K + k)*64 + (c & 63)) : (k*128 + c);
        tmp[j] = f2b(src[sidx]);
    }
    u64 lo = (u64)tmp[0] | ((u64)tmp[1] << 16) | ((u64)tmp[2] << 32) | ((u64)tmp[3] << 48);
    u64 hi = (u64)tmp[4] | ((u64)tmp[5] << 16) | ((u64)tmp[6] << 32) | ((u64)tmp[7] << 48);
    u64* o = (u64*)(dst + (size_t)(dbase + q) * 8);
    o[0] = lo; o[1] = hi;
}

// ---------------------------------------------------------------------------
// Gather + mean, max-TLP: one thread per (node, 16B column chunk).
// 16 independent uint4 loads in flight per thread; fp32 accumulate.
// ---------------------------------------------------------------------------
template<int C>   // 128 or 256 bf16 columns
__global__ void gatherMean(const ushort_t* __restrict__ h,
                           const int* __restrict__ nb,
                           ushort_t* __restrict__ agg)
{
    constexpr int CH = C / 8;                       // 16B chunks per row
    constexpr int SH = (C == 128) ? 4 : 5;
    int t = blockIdx.x * 256 + threadIdx.x;
    int node = t >> SH, c = t & (CH - 1);
    if (node >= NN) return;
    int4 n4[4];
    const int4* np4 = (const int4*)(nb + (size_t)node * SNEI);
#pragma unroll
    for (int i = 0; i < 4; ++i) n4[i] = np4[i];
    const int* nl = (const int*)n4;
    float a0=0.f,a1=0.f,a2=0.f,a3=0.f,a4=0.f,a5=0.f,a6=0.f,a7=0.f;
#pragma unroll
    for (int s = 0; s < SNEI; ++s) {
        uint4 v = *(const uint4*)(h + (size_t)nl[s] * C + c * 8);
        a0 += b2f(v.x & 0xFFFFu); a1 += b2f(v.x >> 16);
        a2 += b2f(v.y & 0xFFFFu); a3 += b2f(v.y >> 16);
        a4 += b2f(v.z & 0xFFFFu); a5 += b2f(v.z >> 16);
        a6 += b2f(v.w & 0xFFFFu); a7 += b2f(v.w >> 16);
    }
    const float M = 0.0625f;
    u64* op = (u64*)(agg + (size_t)node * C + c * 8);
    op[0] = pack4(a0*M, a1*M, a2*M, a3*M);
    op[1] = pack4(a4*M, a5*M, a6*M, a7*M);
}

// ---------------------------------------------------------------------------
// Prep GEMM: h0 = bf16(feats @ prep_W), [50000,256]x[256,128].
// Tile 64 rows, 4 waves (2 along M x 2 along N), BK=64, fragment-major LDS.
// ---------------------------------------------------------------------------
__global__ __launch_bounds__(256, 4)
void prep_gemm(const float* __restrict__ X, const ushort_t* __restrict__ Wp,
               ushort_t* __restrict__ outb)
{
    __shared__ bhalf8 lds[1536];
    u64* l64 = (u64*)lds;
    const int tid = threadIdx.x;
    const int lane = tid & 63;
    const int wid = tid >> 6;
    const int wave_m = wid >> 1, wave_n = wid & 1;
    const int m0 = blockIdx.x * 64;

    facc4 acc[2][4];
    const facc4 z = {0.f, 0.f, 0.f, 0.f};
#pragma unroll
    for (int i = 0; i < 2; ++i)
#pragma unroll
        for (int j = 0; j < 4; ++j) acc[i][j] = z;

    for (int kt = 0; kt < 4; ++kt) {
#pragma unroll
        for (int it = 0; it < 2; ++it) {
            int idx = tid + it * 256;
            int row = idx >> 3, a = idx & 7;
            int grow = m0 + row; if (grow > NN - 1) grow = NN - 1;
            const float4* gp = (const float4*)(X + (size_t)grow * 256 + kt*64 + a*8);
            float4 f0 = gp[0], f1 = gp[1];
            int a2 = a & 3, half = a2 >> 1, g1 = (a2 & 1) << 1;
            int cb = ((a >> 2)*4 + (row >> 4))*64 + (row & 15);
            l64[(cb + g1*16)*2 + half]       = pack4(f0.x, f0.y, f0.z, f0.w);
            l64[(cb + (g1 + 1)*16)*2 + half] = pack4(f1.x, f1.y, f1.z, f1.w);
        }
        {
            const bhalf8* wg = (const bhalf8*)Wp + (size_t)kt * 1024;
#pragma unroll
            for (int it = 0; it < 4; ++it) {
                int idx = tid + it * 256;
                lds[512 + idx] = wg[idx];
            }
        }
        __syncthreads();
        const int nfo = wave_n * 4;
#pragma unroll
        for (int ksl = 0; ksl < 2; ++ksl) {
            bhalf8 a0 = lds[(ksl*4 + wave_m*2 + 0)*64 + lane];
            bhalf8 a1 = lds[(ksl*4 + wave_m*2 + 1)*64 + lane];
#pragma unroll
            for (int nf = 0; nf < 4; ++nf) {
                bhalf8 b = lds[512 + (ksl*8 + nfo + nf)*64 + lane];
                acc[0][nf] = __builtin_amdgcn_mfma_f32_16x16x32_bf16(a0, b, acc[0][nf], 0, 0, 0);
                acc[1][nf] = __builtin_amdgcn_mfma_f32_16x16x32_bf16(a1, b, acc[1][nf], 0, 0, 0);
            }
        }
        __syncthreads();
    }
    const int cl = lane & 15, rg = lane >> 4;
#pragma unroll
    for (int mf2 = 0; mf2 < 2; ++mf2) {
        int rowb = m0 + (wave_m*2 + mf2)*16 + rg*4;
#pragma unroll
        for (int nf = 0; nf < 4; ++nf) {
            int col = (wave_n*4 + nf)*16 + cl;
            facc4 v = acc[mf2][nf];
#pragma unroll
            for (int rr = 0; rr < 4; ++rr) {
                int row = rowb + rr;
                if (row < NN) outb[(size_t)row * 128 + col] = f2b(v[rr]);
            }
        }
    }
}

// ---------------------------------------------------------------------------
// Dual layer GEMM: wave_n=0 -> X@Wx, wave_n=1 -> AGG@Wn, relu,
// head-interleaved fp32 out (pitch 512) at ocol0.
// X and AGG are bf16 [NN, K]. WRH1: also write bf16 copy to h1o [NN,256].
// Tile 64 rows x 256 virtual cols, BK=64, 4 waves, 48KB LDS.
// ---------------------------------------------------------------------------
template<bool WRH1>
__global__ __launch_bounds__(256, 3)
void dual_gemm(const ushort_t* __restrict__ X, const ushort_t* __restrict__ AG,
               const ushort_t* __restrict__ Wxp, const ushort_t* __restrict__ Wnp,
               int K, float* __restrict__ out, int ocol0,
               ushort_t* __restrict__ h1o)
{
    __shared__ bhalf8 lds[3072];
    u64* l64 = (u64*)lds;
    const int tid = threadIdx.x;
    const int lane = tid & 63;
    const int wid = tid >> 6;
    const int wave_m = wid >> 1, wave_n = wid & 1;
    const int m0 = blockIdx.x * 64;

    facc4 acc[2][8];
    const facc4 z = {0.f, 0.f, 0.f, 0.f};
#pragma unroll
    for (int i = 0; i < 2; ++i)
#pragma unroll
        for (int j = 0; j < 8; ++j) acc[i][j] = z;

    const int K64 = K >> 6;
    for (int kt = 0; kt < K64; ++kt) {
#pragma unroll
        for (int it = 0; it < 2; ++it) {
            int idx = tid + it * 256;              // (row, 8-elem chunk a)
            int row = idx >> 3, a = idx & 7;
            int grow = m0 + row; if (grow > NN - 1) grow = NN - 1;
            int coff = kt*64 + a*8;
            int a2 = a & 3, half = a2 >> 1, g1 = (a2 & 1) << 1;
            int cb = ((a >> 2)*4 + (row >> 4))*64 + (row & 15);
            const u64* gx = (const u64*)(X  + (size_t)grow * K + coff);
            const u64* ga = (const u64*)(AG + (size_t)grow * K + coff);
            l64[(cb + g1*16)*2 + half]              = gx[0];
            l64[(cb + (g1 + 1)*16)*2 + half]        = gx[1];
            l64[1024 + (cb + g1*16)*2 + half]       = ga[0];
            l64[1024 + (cb + (g1 + 1)*16)*2 + half] = ga[1];
        }
        {   // W stage (linear copy of pre-permuted chunks)
            const bhalf8* wgx = (const bhalf8*)Wxp + (size_t)kt * 1024;
            const bhalf8* wgn = (const bhalf8*)Wnp + (size_t)kt * 1024;
#pragma unroll
            for (int it = 0; it < 4; ++it) {
                int idx = tid + it * 256;
                lds[1024 + idx] = wgx[idx];
                lds[2048 + idx] = wgn[idx];
            }
        }
        __syncthreads();
        const int aB = wave_n ? 512 : 0;
        const int wB = wave_n ? 2048 : 1024;
#pragma unroll
        for (int ksl = 0; ksl < 2; ++ksl) {
            bhalf8 a0 = lds[aB + (ksl*4 + wave_m*2 + 0)*64 + lane];
            bhalf8 a1 = lds[aB + (ksl*4 + wave_m*2 + 1)*64 + lane];
#pragma unroll
            for (int nf = 0; nf < 8; ++nf) {
                bhalf8 b = lds[wB + (ksl*8 + nf)*64 + lane];
                acc[0][nf] = __builtin_amdgcn_mfma_f32_16x16x32_bf16(a0, b, acc[0][nf], 0, 0, 0);
                acc[1][nf] = __builtin_amdgcn_mfma_f32_16x16x32_bf16(a1, b, acc[1][nf], 0, 0, 0);
            }
        }
        __syncthreads();
    }
    // epilogue: D mapping col=lane&15, row=(lane>>4)*4+reg; relu; interleave
    const int cl = lane & 15, rg = lane >> 4;
#pragma unroll
    for (int mf2 = 0; mf2 < 2; ++mf2) {
        int rowb = m0 + (wave_m*2 + mf2)*16 + rg*4;
#pragma unroll
        for (int nf = 0; nf < 8; ++nf) {
            int cpr = nf*16 + cl;
            int icol = (cpr >> 6)*128 + wave_n*64 + (cpr & 63);
            facc4 v = acc[mf2][nf];
#pragma unroll
            for (int rr = 0; rr < 4; ++rr) {
                int row = rowb + rr;
                if (row < NN) {
                    float f = fmaxf(v[rr], 0.0f);
                    out[(size_t)row * 512 + ocol0 + icol] = f;
                    if constexpr (WRH1)
                        h1o[(size_t)row * 256 + icol] = f2b(f);
                }
            }
        }
    }
}

// ---------------------------------------------------------------------------
extern "C" void kernel_launch(void* const* d_in, const int* in_sizes, int n_in,
                              void* d_out, int out_size, void* d_ws, size_t ws_size,
                              hipStream_t stream)
{
    const float* feats  = (const float*)d_in[0];
    const float* prepWp = (const float*)d_in[1];
    const float* Wx1    = (const float*)d_in[2];
    const float* Wn1    = (const float*)d_in[3];
    const float* Wx2    = (const float*)d_in[4];
    const float* Wn2    = (const float*)d_in[5];
    const int*   neigh  = (const int*)d_in[6];
    float* out = (float*)d_out;
    ushort_t* ws = (ushort_t*)d_ws;

    ushort_t* perm = ws;                          // 229376 bf16 (458.75 KB)
    ushort_t* h0   = ws + 229376;                 // 50000*128 bf16 (12.8 MB)
    ushort_t* h1   = h0 + (size_t)NN * 128;       // 50000*256 bf16 (25.6 MB)
    ushort_t* agg  = h1 + (size_t)NN * 256;       // 50000*256 bf16 (25.6 MB)

    permW<<<112, 256, 0, stream>>>(prepWp, Wx1, Wn1, Wx2, Wn2, perm);

    const int GB = (NN + 63) / 64;                // 782
    prep_gemm<<<GB, 256, 0, stream>>>(feats, perm, h0);

    for (int mp = 0; mp < 2; ++mp) {
        float* omp = out + (size_t)mp * NN * 512;
        const int* nmp = neigh + (size_t)mp * NN * SNEI;

        gatherMean<128><<<(NN * SNEI) / 256, 256, 0, stream>>>(h0, nmp, agg);
        dual_gemm<true><<<GB, 256, 0, stream>>>(h0, agg,
            perm + (size_t)(4096  + mp*2048) * 8,
            perm + (size_t)(8192  + mp*2048) * 8,
            128, omp, 0, h1);

        gatherMean<256><<<(NN * SNEI * 2) / 256, 256, 0, stream>>>(h1, nmp, agg);
        dual_gemm<false><<<GB, 256, 0, stream>>>(h1, agg,
            perm + (size_t)(12288 + mp*4096) * 8,
            perm + (size_t)(20480 + mp*4096) * 8,
            256, omp, 256, nullptr);
    }
}

// Round 5
// 193.187 us; speedup vs baseline: 2.1669x; 1.4360x over previous
//
#include <hip/hip_runtime.h>

#define NN 50000
#define SNEI 16
#define GB 782            // ceil(50000/64)

typedef unsigned short ushort_t;
typedef unsigned int uint_t;
typedef unsigned long long u64;
typedef __attribute__((ext_vector_type(8))) short bhalf8;
typedef __attribute__((ext_vector_type(4))) float facc4;

__device__ __forceinline__ float b2f(uint_t u) {
    union { uint_t u; float f; } x; x.u = u << 16; return x.f;
}
__device__ __forceinline__ ushort_t f2b(float f) {
    union { float f; uint_t u; } x; x.f = f;
    return (ushort_t)((x.u + 0x7FFFu + ((x.u >> 16) & 1u)) >> 16);
}
__device__ __forceinline__ u64 pack4(float a, float b, float c, float d) {
    return (u64)f2b(a) | ((u64)f2b(b) << 16) | ((u64)f2b(c) << 32) | ((u64)f2b(d) << 48);
}

typedef const __attribute__((address_space(1))) void cglb_t;
typedef __attribute__((address_space(3))) void lds3_t;
__device__ __forceinline__ void gload16(const void* g, void* l) {
    __builtin_amdgcn_global_load_lds((cglb_t*)g, (lds3_t*)l, 16, 0, 0);
}

// ---------------------------------------------------------------------------
// One-time weight setup. Fragment k-bijection: chunk (ks*8+nf)*64+lane,
// elem j of lane l holds W[k][c] with k = ks*32 + (l>>4)*8 + j (16B-contig!),
// c = nf*16 + (l&15). Same bijection used by all A-staging paths.
// Layer-1 weights are pre-multiplied by prepW: W'1 = prepW @ W1  [256,128].
// perm layout (chunks): [L1: mp0{x 4096|n 4096} mp1{...}][L2: same] = 32768.
// One thread per OUTPUT ELEMENT (262144 total).
// ---------------------------------------------------------------------------
__global__ void permSetup(const float* __restrict__ prepW,
                          const float* __restrict__ Wx1, const float* __restrict__ Wn1,
                          const float* __restrict__ Wx2, const float* __restrict__ Wn2,
                          ushort_t* __restrict__ dst)
{
    int e = blockIdx.x * 256 + threadIdx.x;
    int q8 = e >> 3, j = e & 7;
    int layer = q8 >> 14;
    int qq = q8 & 16383;
    int mp = qq >> 13, isN = (qq >> 12) & 1, q = qq & 4095;
    int lane = q & 63, nf = (q >> 6) & 7, ks = q >> 9;
    int c = nf * 16 + (lane & 15);                 // [0,128)
    int k = ks * 32 + ((lane >> 4) << 3) + j;      // [0,256)
    float v;
    if (layer == 0) {
        const float* W1 = (isN ? Wn1 : Wx1) + mp * 16384 + (c >> 6) * 8192 + (c & 63);
        const float* pw = prepW + (size_t)k * 128;
        float s = 0.f;
#pragma unroll 8
        for (int p = 0; p < 128; ++p) s += pw[p] * W1[(size_t)p * 64];
        v = s;
    } else {
        const float* W2 = (isN ? Wn2 : Wx2) + mp * 32768 + (c >> 6) * 16384 + (size_t)k * 64 + (c & 63);
        v = *W2;
    }
    dst[(size_t)q8 * 8 + j] = f2b(v);
}

// ---------------------------------------------------------------------------
// Dual-projection GEMM, K=256 always. wave_n=0: Xh = X@Wx -> relu -> fp32 out
// (head-interleaved x-slots at obase), optionally bf16 h1 x-part (L1).
// wave_n=1: P = X@Wn -> bf16 P [N,128] (NO relu; mean+relu happen in gather).
// XF32: X fp32 (feats, converted during staging); else bf16 via gload_lds.
// Tile 64 rows x 128 cols/role, BK=64, 4 waves, 40KB LDS, 4 blocks/CU.
// LDS chunks: X [0,512) | Wx [512,1536) | Wn [1536,2560).
// ---------------------------------------------------------------------------
template<bool XF32, bool L1>
__global__ __launch_bounds__(256, 4)
void proj_gemm(const void* __restrict__ Xv, size_t xStr,
               const ushort_t* __restrict__ W, size_t wStr,
               float* __restrict__ out, size_t oStr,
               ushort_t* __restrict__ h1, size_t hStr,
               ushort_t* __restrict__ P, size_t PStr)
{
    __shared__ bhalf8 lds[2560];
    u64* l64 = (u64*)lds;
    const int tid = threadIdx.x;
    const int lane = tid & 63;
    const int wid = tid >> 6;
    const int wave_m = wid >> 1, wave_n = wid & 1;
    const int m0 = blockIdx.x * 64;
    const int mp = blockIdx.y;

    const ushort_t* wx = W + (size_t)mp * wStr;
    const ushort_t* wn = wx + 4096 * 8;
    const float*    Xf = (const float*)Xv    + (size_t)mp * xStr;
    const ushort_t* Xb = (const ushort_t*)Xv + (size_t)mp * xStr;
    float* outp = out + (size_t)mp * oStr;
    ushort_t* h1p = L1 ? (h1 + (size_t)mp * hStr) : nullptr;
    ushort_t* Pp  = P + (size_t)mp * PStr;

    facc4 acc[2][8];
    const facc4 z = {0.f, 0.f, 0.f, 0.f};
#pragma unroll
    for (int i = 0; i < 2; ++i)
#pragma unroll
        for (int j = 0; j < 8; ++j) acc[i][j] = z;

    for (int kt = 0; kt < 4; ++kt) {
        // ---- X stage: frag chunk s holds rows m0+mf*16+(s&15), k-slice ----
        if constexpr (XF32) {
#pragma unroll
            for (int it = 0; it < 2; ++it) {
                int s = tid + it * 256;              // [0,512)
                int fp = s >> 6, ls = s & 63;
                int mf = fp & 3, ksl = fp >> 2;
                int grow = m0 + mf * 16 + (ls & 15); if (grow > NN - 1) grow = NN - 1;
                const float* gp = Xf + (size_t)grow * 256 + kt * 64 + ksl * 32 + ((ls >> 4) << 3);
                float4 f0 = *(const float4*)gp, f1 = *(const float4*)(gp + 4);
                l64[s * 2]     = pack4(f0.x, f0.y, f0.z, f0.w);
                l64[s * 2 + 1] = pack4(f1.x, f1.y, f1.z, f1.w);
            }
        } else {
#pragma unroll
            for (int it = 0; it < 2; ++it) {
                int u = wid + it * 4;                // fragpos 0..7
                int mf = u & 3, ksl = u >> 2;
                int grow = m0 + mf * 16 + (lane & 15); if (grow > NN - 1) grow = NN - 1;
                const ushort_t* src = Xb + (size_t)grow * 256 + kt * 64 + ksl * 32 + ((lane >> 4) << 3);
                gload16(src, (char*)lds + (u * 64 + lane) * 16);
            }
        }
        // ---- W stage: linear gload_lds of pre-permuted chunks ----
#pragma unroll
        for (int it = 0; it < 4; ++it) {
            int cb = (it * 4 + wid) * 64;            // [0,1024)
            gload16(wx + ((size_t)kt * 1024 + cb + lane) * 8,
                    (char*)lds + (512 + cb + lane) * 16);
            gload16(wn + ((size_t)kt * 1024 + cb + lane) * 8,
                    (char*)lds + (1536 + cb + lane) * 16);
        }
        __syncthreads();
        // ---- compute ----
        const int wB = wave_n ? 1536 : 512;
#pragma unroll
        for (int ksl = 0; ksl < 2; ++ksl) {
            bhalf8 a0 = lds[(ksl * 4 + wave_m * 2 + 0) * 64 + lane];
            bhalf8 a1 = lds[(ksl * 4 + wave_m * 2 + 1) * 64 + lane];
#pragma unroll
            for (int nf = 0; nf < 8; ++nf) {
                bhalf8 b = lds[wB + (ksl * 8 + nf) * 64 + lane];
                acc[0][nf] = __builtin_amdgcn_mfma_f32_16x16x32_bf16(a0, b, acc[0][nf], 0, 0, 0);
                acc[1][nf] = __builtin_amdgcn_mfma_f32_16x16x32_bf16(a1, b, acc[1][nf], 0, 0, 0);
            }
        }
        __syncthreads();
    }
    // ---- epilogue: D map col=lane&15, row=(lane>>4)*4+reg ----
    const int cl = lane & 15, rg = lane >> 4;
    const int obase = L1 ? 0 : 256;
#pragma unroll
    for (int mf2 = 0; mf2 < 2; ++mf2) {
        int rowb = m0 + (wave_m * 2 + mf2) * 16 + rg * 4;
#pragma unroll
        for (int nf = 0; nf < 8; ++nf) {
            int cpr = nf * 16 + cl;                  // [0,128)
            int icol = (cpr >> 6) * 128 + (cpr & 63);
            facc4 v = acc[mf2][nf];
#pragma unroll
            for (int rr = 0; rr < 4; ++rr) {
                int row = rowb + rr;
                if (row < NN) {
                    if (wave_n == 0) {
                        float f = fmaxf(v[rr], 0.0f);
                        outp[(size_t)row * 512 + obase + icol] = f;
                        if constexpr (L1)
                            h1p[(size_t)row * 256 + icol] = f2b(f);
                    } else {
                        Pp[(size_t)row * 128 + cpr] = f2b(v[rr]);
                    }
                }
            }
        }
    }
}

// ---------------------------------------------------------------------------
// Gather + mean + relu, writing final n-slots of out (fp32) and, for L1,
// the h1 n-part (bf16). Block = 16 nodes x 16 chunks; indices staged in LDS.
// ---------------------------------------------------------------------------
template<bool L1>
__global__ __launch_bounds__(256)
void gatherK(const ushort_t* __restrict__ P, size_t PStr,
             const int* __restrict__ nb, size_t nStr,
             float* __restrict__ out, size_t oStr,
             ushort_t* __restrict__ h1, size_t hStr)
{
    const int mp = blockIdx.y;
    const ushort_t* Pp = P + (size_t)mp * PStr;
    const int* nbp = nb + (size_t)mp * nStr;
    float* outp = out + (size_t)mp * oStr;

    __shared__ int nls[256];
    const int nodeBase = blockIdx.x * 16;
    nls[threadIdx.x] = nbp[(size_t)nodeBase * SNEI + threadIdx.x];
    __syncthreads();

    const int nl = threadIdx.x >> 4, c = threadIdx.x & 15;
    const int node = nodeBase + nl;
    const int* nr = nls + nl * SNEI;
    float a0=0.f,a1=0.f,a2=0.f,a3=0.f,a4=0.f,a5=0.f,a6=0.f,a7=0.f;
#pragma unroll
    for (int s = 0; s < SNEI; ++s) {
        uint4 v = *(const uint4*)(Pp + (size_t)nr[s] * 128 + c * 8);
        a0 += b2f(v.x & 0xFFFFu); a1 += b2f(v.x >> 16);
        a2 += b2f(v.y & 0xFFFFu); a3 += b2f(v.y >> 16);
        a4 += b2f(v.z & 0xFFFFu); a5 += b2f(v.z >> 16);
        a6 += b2f(v.w & 0xFFFFu); a7 += b2f(v.w >> 16);
    }
    const float M = 0.0625f;
    float r0 = fmaxf(a0*M, 0.f), r1 = fmaxf(a1*M, 0.f);
    float r2 = fmaxf(a2*M, 0.f), r3 = fmaxf(a3*M, 0.f);
    float r4 = fmaxf(a4*M, 0.f), r5 = fmaxf(a5*M, 0.f);
    float r6 = fmaxf(a6*M, 0.f), r7 = fmaxf(a7*M, 0.f);
    const int head = c >> 3, off = (c & 7) * 8;
    const int obase = L1 ? 0 : 256;
    float* o = outp + (size_t)node * 512 + obase + head * 128 + 64 + off;
    *(float4*)o       = make_float4(r0, r1, r2, r3);
    *(float4*)(o + 4) = make_float4(r4, r5, r6, r7);
    if constexpr (L1) {
        ushort_t* hp = h1 + (size_t)mp * hStr + (size_t)node * 256 + head * 128 + 64 + off;
        *(u64*)hp       = pack4(r0, r1, r2, r3);
        *(u64*)(hp + 4) = pack4(r4, r5, r6, r7);
    }
}

// ---------------------------------------------------------------------------
extern "C" void kernel_launch(void* const* d_in, const int* in_sizes, int n_in,
                              void* d_out, int out_size, void* d_ws, size_t ws_size,
                              hipStream_t stream)
{
    const float* feats  = (const float*)d_in[0];
    const float* prepWp = (const float*)d_in[1];
    const float* Wx1    = (const float*)d_in[2];
    const float* Wn1    = (const float*)d_in[3];
    const float* Wx2    = (const float*)d_in[4];
    const float* Wn2    = (const float*)d_in[5];
    const int*   neigh  = (const int*)d_in[6];
    float* out = (float*)d_out;
    ushort_t* ws = (ushort_t*)d_ws;

    const size_t permElems = 262144;                       // 512 KB
    const size_t needBatched = permElems * 2
        + 2 * ((size_t)NN * 128 * 2 + (size_t)NN * 256 * 2);  // 77.3 MB
    const bool batched = ws_size >= needBatched;
    const int nmp = batched ? 2 : 1;

    ushort_t* perm = ws;
    ushort_t* P    = ws + permElems;                        // nmp * NN*128
    ushort_t* h1   = P + (size_t)nmp * NN * 128;            // nmp * NN*256

    permSetup<<<1024, 256, 0, stream>>>(prepWp, Wx1, Wn1, Wx2, Wn2, perm);

    const size_t PStr = batched ? (size_t)NN * 128 : 0;
    const size_t hStr = batched ? (size_t)NN * 256 : 0;
    const size_t oStr = batched ? (size_t)NN * 512 : 0;
    const size_t nStr = batched ? (size_t)NN * SNEI : 0;
    const size_t wStr = batched ? (size_t)8192 * 8 : 0;
    const int passes = batched ? 1 : 2;

    for (int p = 0; p < passes; ++p) {
        const ushort_t* w1 = perm + (size_t)p * 8192 * 8;
        const ushort_t* w2 = perm + (size_t)(16384 + p * 8192) * 8;
        float* outp = out + (size_t)p * NN * 512;
        const int* nbp = neigh + (size_t)p * NN * SNEI;
        dim3 gp(GB, nmp), gg(NN / 16, nmp);

        proj_gemm<true, true><<<gp, 256, 0, stream>>>(
            feats, 0, w1, wStr, outp, oStr, h1, hStr, P, PStr);
        gatherK<true><<<gg, 256, 0, stream>>>(
            P, PStr, nbp, nStr, outp, oStr, h1, hStr);
        proj_gemm<false, false><<<gp, 256, 0, stream>>>(
            h1, hStr, w2, wStr, outp, oStr, nullptr, 0, P, PStr);
        gatherK<false><<<gg, 256, 0, stream>>>(
            P, PStr, nbp, nStr, outp, oStr, nullptr, 0);
    }
}